// Round 15
// baseline (1661247.266 us; speedup 1.0000x reference)
//
#include <hip/hip_runtime.h>
#include <math.h>

#define T_STEPS 128
#define B_SZ 128
#define D_SZ 1024
#define H_SZ 1024
#define G4 4096
#define KW 2048  // rows of W = D+H

typedef __attribute__((ext_vector_type(8))) short bf16x8;
typedef __attribute__((ext_vector_type(4))) float f32x4;
typedef unsigned short ushort_t;
typedef unsigned int uint_t;
typedef unsigned long long ull_t;

__device__ __forceinline__ float sigf(float x) { return 1.0f / (1.0f + __expf(-x)); }
__device__ __forceinline__ float tanhfast(float x) { return 1.0f - 2.0f * sigf(-2.0f * x); }

__device__ __forceinline__ ushort_t f2bf(float f) {
  uint_t u = __float_as_uint(f);
  return (ushort_t)((u + 0x7fffu + ((u >> 16) & 1u)) >> 16);
}
__device__ __forceinline__ float bf2f(ushort_t s) {
  return __uint_as_float(((uint_t)s) << 16);
}

#define GLOAD_LDS16(gp, lp)                                                  \
  __builtin_amdgcn_global_load_lds(                                          \
      (const __attribute__((address_space(1))) unsigned int*)(const void*)(gp), \
      (__attribute__((address_space(3))) unsigned int*)(void*)(lp), 16, 0, 0)

// ---------------------------------------------------------------------------
// x fp32 [16384][1024] -> bf16 same layout. 8 elems/thread.
// ---------------------------------------------------------------------------
__global__ __launch_bounds__(256) void convert_x(const float* __restrict__ x,
                                                 ushort_t* __restrict__ xbf) {
  const size_t i8 = ((size_t)blockIdx.x * 256 + threadIdx.x) * 8;
  if (i8 + 8 > (size_t)T_STEPS * B_SZ * D_SZ) return;
  float4 a = *(const float4*)&x[i8];
  float4 b = *(const float4*)&x[i8 + 4];
  ushort_t o[8] = {f2bf(a.x), f2bf(a.y), f2bf(a.z), f2bf(a.w),
                   f2bf(b.x), f2bf(b.y), f2bf(b.z), f2bf(b.w)};
  *(uint4*)&xbf[i8] = *(uint4*)o;
}

// ---------------------------------------------------------------------------
// W fp32 [2048][4096] -> WT bf16 [4096][2048]  (WT[n][k] = W[k][n])
// ---------------------------------------------------------------------------
__global__ __launch_bounds__(256) void transpose_w(const float* __restrict__ W,
                                                   ushort_t* __restrict__ WT) {
  __shared__ float t[32][33];
  const int tx = threadIdx.x & 31;
  const int ty = threadIdx.x >> 5;  // 0..7
  const int k0 = blockIdx.x * 32;
  const int n0 = blockIdx.y * 32;
#pragma unroll
  for (int i = 0; i < 4; ++i)
    t[ty + i * 8][tx] = W[(size_t)(k0 + ty + i * 8) * G4 + n0 + tx];
  __syncthreads();
#pragma unroll
  for (int i = 0; i < 4; ++i)
    WT[(size_t)(n0 + ty + i * 8) * KW + k0 + tx] = f2bf(t[tx][ty + i * 8]);
}

// ---------------------------------------------------------------------------
// hbf0 = bf16(h0 * (1-reset[0]))
// ---------------------------------------------------------------------------
__global__ __launch_bounds__(256) void init_state(const float* __restrict__ h0,
                                                  const float* __restrict__ reset0,
                                                  ushort_t* __restrict__ hbf0) {
  const int i = blockIdx.x * 256 + threadIdx.x;
  if (i >= B_SZ * H_SZ) return;
  hbf0[i] = f2bf(h0[i] * (1.0f - reset0[i >> 10]));
}

// ---------------------------------------------------------------------------
// Gate pre-activation from x (v3 layout, supertile-swizzled). Unchanged R11.
//   elem idx = (((t*4 + btp)*64 + jt)*2048) + g*512 + c*32 + r32
//   m = t*128 + btp*32 + r32, n = g*1024 + jt*16 + c.
// ---------------------------------------------------------------------------
__global__ __launch_bounds__(256) void xw_mfma3(const ushort_t* __restrict__ xbf,
                                                const ushort_t* __restrict__ WT,
                                                const float* __restrict__ bias,
                                                ushort_t* __restrict__ xwg) {
  __shared__ ushort_t Asb[2][128 * 64];
  __shared__ ushort_t Bsb[2][128 * 64];

  const int bid = blockIdx.x;
  const int xcd = bid & 7;
  const int ib = bid >> 3;
  const int mt = (ib >> 5) * 8 + (ib & 7);
  const int nt = xcd * 4 + ((ib >> 3) & 3);
  const int m0 = mt * 128, n0 = nt * 128;
  const int tid = threadIdx.x, lane = tid & 63, wid = tid >> 6;
  const int wr = wid >> 1, wc = wid & 1;
  const int lr = lane & 15, ko = lane >> 4;
  const int srow = lane >> 3;
  const int skb = (lane & 7) * 16;

  f32x4 acc[4][4] = {};

#define XW_STAGE(buf, kt)                                                      \
  {                                                                            \
    const int k0b = (kt) * 128;                                                \
    _Pragma("unroll") for (int i = 0; i < 4; ++i) {                            \
      const int c = wid * 4 + i;                                               \
      const int row = c * 8 + srow;                                            \
      const int sw = skb ^ ((row & 7) << 4);                                   \
      GLOAD_LDS16((const char*)xbf + (size_t)(m0 + row) * 2048 + k0b + sw,     \
                  (char*)&Asb[buf][0] + c * 1024);                             \
      GLOAD_LDS16((const char*)WT + (size_t)(n0 + row) * 4096 + k0b + sw,      \
                  (char*)&Bsb[buf][0] + c * 1024);                             \
    }                                                                          \
  }

  XW_STAGE(0, 0);
  __syncthreads();
  const int xsw = (lr & 7) << 4;
  for (int kt = 0; kt < 16; ++kt) {
    if (kt + 1 < 16) XW_STAGE((kt + 1) & 1, kt + 1);
    const char* Ab = (const char*)&Asb[kt & 1][0] + (wr * 64 + lr) * 128;
    const char* Bb = (const char*)&Bsb[kt & 1][0] + (wc * 64 + lr) * 128;
#pragma unroll
    for (int ks = 0; ks < 2; ++ks) {
      const int kb = (ks * 64 + ko * 16) ^ xsw;
      bf16x8 a[4], b[4];
#pragma unroll
      for (int mi = 0; mi < 4; ++mi) a[mi] = *(const bf16x8*)(Ab + mi * 2048 + kb);
#pragma unroll
      for (int ni = 0; ni < 4; ++ni) b[ni] = *(const bf16x8*)(Bb + ni * 2048 + kb);
#pragma unroll
      for (int mi = 0; mi < 4; ++mi)
#pragma unroll
        for (int ni = 0; ni < 4; ++ni)
          acc[mi][ni] = __builtin_amdgcn_mfma_f32_16x16x32_bf16(a[mi], b[ni], acc[mi][ni], 0, 0, 0);
    }
    __syncthreads();
  }

  const int rr = ko * 4;
#pragma unroll
  for (int ni = 0; ni < 4; ++ni) {
    const int n = n0 + wc * 64 + ni * 16 + lr;
    const int g = n >> 10;
    const int jtn = (n & 1023) >> 4;
    const float bn = bias[n];
#pragma unroll
    for (int mi = 0; mi < 4; ++mi) {
      const int m = m0 + wr * 64 + mi * 16 + rr;
      const int tt = m >> 7;
      const int btp = (m & 127) >> 5;
      const int r32 = m & 31;
      ushort_t tmp[4];
#pragma unroll
      for (int r = 0; r < 4; ++r) tmp[r] = f2bf(acc[mi][ni][r] + bn);
      *(ull_t*)(xwg + (((size_t)tt * 4 + btp) * 64 + jtn) * 2048 + g * 512 + lr * 32 + r32) =
          *(ull_t*)tmp;
    }
  }
}

// ---------------------------------------------------------------------------
// Persistent LSTM recurrence v7 (R12 verbatim — known-good 597us).
// ---------------------------------------------------------------------------
__global__ __launch_bounds__(512) void lstm_persist7(
    const ushort_t* __restrict__ hbf0,
    const float* __restrict__ c0,
    const float* __restrict__ reset,
    const ushort_t* __restrict__ xwg,
    const ushort_t* __restrict__ WT,
    float* __restrict__ out,
    ushort_t* __restrict__ hring,
    uint_t* __restrict__ bar) {
  __shared__ ushort_t WhL[64 * 512];
  __shared__ ushort_t Ah[32 * 1024];
  __shared__ float sc[2][4][16][17];

  const int tid = threadIdx.x;
  const int bid = blockIdx.x;
  const int jt = bid & 63;
  const int btp = bid >> 6;
  const int b0 = btp * 32;
  const int lane = tid & 63;
  const int wid = tid >> 6;
  const int g = wid & 3;
  const int mh = wid >> 2;
  const int lr = lane & 15;
  const int ko = lane >> 4;
  const size_t SE = (size_t)B_SZ * H_SZ;

  uint_t* const arr = bar + btp * 256;

  for (int p = 0; p < 8; ++p) {
    const int id = p * 512 + tid;
    const int wrw = id >> 6;
    const int kb = (id & 63) * 16;
    const int n = (wrw >> 4) * H_SZ + jt * 16 + (wrw & 15);
    const uint4 v = *(const uint4*)((const char*)WT + (size_t)n * 4096 + 2048 + kb);
    *(uint4*)((char*)WhL + wrw * 1024 + (kb ^ ((wrw & 7) << 4))) = v;
  }

  const char* wrow = (const char*)WT + (size_t)(g * H_SZ + jt * 16 + lr) * 4096;
  bf16x8 breg[16];
#pragma unroll
  for (int q = 0; q < 16; ++q)
    breg[q] = *(const bf16x8*)(wrow + 3072 + q * 64 + ko * 16);

  const int row = tid >> 4;
  const int col = tid & 15;
  const int b = b0 + row;
  const int j = jt * 16 + col;
  const size_t so = (size_t)b * H_SZ + j;
  float creg = c0[so] * (1.0f - reset[b]);

  const int swzl = (lr & 7) << 4;
  const char* aBase = (const char*)Ah + (mh * 16 + lr) * 2048;
  const char* bBase = (const char*)WhL + (g * 16 + lr) * 1024;

  ushort_t xq0, xq1, xq2, xq3;
  {
    const ushort_t* xp = xwg + (((size_t)btp) * 64 + jt) * 2048 + col * 32 + row;
    xq0 = xp[0]; xq1 = xp[512]; xq2 = xp[1024]; xq3 = xp[1536];
  }
  float mn = 1.0f - reset[B_SZ + b];

  for (int t = 0; t < T_STEPS; ++t) {
    if (t > 0) {
      if (wid == 0) {
        uint_t it = 0;
        for (;;) {
          const uint_t v = __hip_atomic_load(&arr[lane], __ATOMIC_RELAXED,
                                             __HIP_MEMORY_SCOPE_AGENT);
          if (__all((int)v >= t)) break;
          __builtin_amdgcn_s_sleep(1);
          if (++it > 1000000u) break;
        }
      }
      __syncthreads();
    }
    const char* hsrc = (t == 0) ? (const char*)hbf0
                                : (const char*)(hring + (size_t)t * SE);
#pragma unroll
    for (int i = 0; i < 8; ++i) {
      const int c = wid * 8 + i;
      const int hrow = c >> 1;
      const int half = (c & 1) * 1024;
      const int kb = half + lane * 16;
      const int src = kb ^ ((hrow & 7) << 4);
      GLOAD_LDS16(hsrc + (size_t)(b0 + hrow) * 2048 + src,
                  (char*)Ah + hrow * 2048 + half);
    }
    __syncthreads();

    f32x4 ac0 = {}, ac1 = {}, ac2 = {}, ac3 = {};
#pragma unroll
    for (int q = 0; q < 4; ++q) {
      bf16x8 a0 = *(const bf16x8*)(aBase + (((q * 4 + 0) * 64 + ko * 16) ^ swzl));
      bf16x8 b0f = *(const bf16x8*)(bBase + (((q * 4 + 0) * 64 + ko * 16) ^ swzl));
      ac0 = __builtin_amdgcn_mfma_f32_16x16x32_bf16(a0, b0f, ac0, 0, 0, 0);
      bf16x8 a1 = *(const bf16x8*)(aBase + (((q * 4 + 1) * 64 + ko * 16) ^ swzl));
      bf16x8 b1f = *(const bf16x8*)(bBase + (((q * 4 + 1) * 64 + ko * 16) ^ swzl));
      ac1 = __builtin_amdgcn_mfma_f32_16x16x32_bf16(a1, b1f, ac1, 0, 0, 0);
      bf16x8 a2 = *(const bf16x8*)(aBase + (((q * 4 + 2) * 64 + ko * 16) ^ swzl));
      bf16x8 b2f = *(const bf16x8*)(bBase + (((q * 4 + 2) * 64 + ko * 16) ^ swzl));
      ac2 = __builtin_amdgcn_mfma_f32_16x16x32_bf16(a2, b2f, ac2, 0, 0, 0);
      bf16x8 a3 = *(const bf16x8*)(aBase + (((q * 4 + 3) * 64 + ko * 16) ^ swzl));
      bf16x8 b3f = *(const bf16x8*)(bBase + (((q * 4 + 3) * 64 + ko * 16) ^ swzl));
      ac3 = __builtin_amdgcn_mfma_f32_16x16x32_bf16(a3, b3f, ac3, 0, 0, 0);
    }
#pragma unroll
    for (int q = 0; q < 4; ++q) {
      bf16x8 a0 = *(const bf16x8*)(aBase + (((16 + q * 4 + 0) * 64 + ko * 16) ^ swzl));
      ac0 = __builtin_amdgcn_mfma_f32_16x16x32_bf16(a0, breg[q * 4 + 0], ac0, 0, 0, 0);
      bf16x8 a1 = *(const bf16x8*)(aBase + (((16 + q * 4 + 1) * 64 + ko * 16) ^ swzl));
      ac1 = __builtin_amdgcn_mfma_f32_16x16x32_bf16(a1, breg[q * 4 + 1], ac1, 0, 0, 0);
      bf16x8 a2 = *(const bf16x8*)(aBase + (((16 + q * 4 + 2) * 64 + ko * 16) ^ swzl));
      ac2 = __builtin_amdgcn_mfma_f32_16x16x32_bf16(a2, breg[q * 4 + 2], ac2, 0, 0, 0);
      bf16x8 a3 = *(const bf16x8*)(aBase + (((16 + q * 4 + 3) * 64 + ko * 16) ^ swzl));
      ac3 = __builtin_amdgcn_mfma_f32_16x16x32_bf16(a3, breg[q * 4 + 3], ac3, 0, 0, 0);
    }
    const f32x4 acc = (ac0 + ac1) + (ac2 + ac3);
#pragma unroll
    for (int r = 0; r < 4; ++r) sc[mh][g][ko * 4 + r][lr] = acc[r];
    __syncthreads();

    const float gi = sc[row >> 4][0][row & 15][col] + bf2f(xq0);
    const float gg = sc[row >> 4][1][row & 15][col] + bf2f(xq1);
    const float gf = sc[row >> 4][2][row & 15][col] + bf2f(xq2);
    const float go = sc[row >> 4][3][row & 15][col] + bf2f(xq3);
    const float f = sigf(gf + 1.0f);
    const float cn = f * creg + sigf(gi) * tanhfast(gg);
    const float hn = sigf(go) * tanhfast(cn);
    creg = cn * mn;

    if (t < T_STEPS - 1) {
      const uint_t hm = (uint_t)f2bf(hn * mn);
      const uint_t h1 = (uint_t)__shfl_down((int)hm, 1);
      const uint_t h2 = (uint_t)__shfl_down((int)hm, 2);
      const uint_t h3 = (uint_t)__shfl_down((int)hm, 3);
      if ((col & 3) == 0) {
        const ull_t pk = (ull_t)(hm & 0xffffu) | ((ull_t)(h1 & 0xffffu) << 16) |
                         ((ull_t)(h2 & 0xffffu) << 32) | ((ull_t)(h3 & 0xffffu) << 48);
        __hip_atomic_store((ull_t*)(hring + (size_t)(t + 1) * SE + so), pk,
                           __ATOMIC_RELAXED, __HIP_MEMORY_SCOPE_AGENT);
      }
      asm volatile("s_waitcnt vmcnt(0)" ::: "memory");
      __syncthreads();
      if (tid == 0)
        __hip_atomic_store(&arr[jt], (uint_t)(t + 1),
                           __ATOMIC_RELAXED, __HIP_MEMORY_SCOPE_AGENT);
      out[(size_t)t * SE + so] = hn;
      const ushort_t* xp = xwg + (((size_t)(t + 1) * 4 + btp) * 64 + jt) * 2048 + col * 32 + row;
      xq0 = xp[0]; xq1 = xp[512]; xq2 = xp[1024]; xq3 = xp[1536];
      mn = (t + 1 < T_STEPS - 1) ? (1.0f - reset[(size_t)(t + 2) * B_SZ + b]) : 1.0f;
    } else {
      out[(size_t)t * SE + so] = hn;
      float* hT = out + (size_t)T_STEPS * SE;
      float* cT = hT + SE;
      hT[so] = hn;
      cT[so] = cn;
    }
  }
}

// ---------------------------------------------------------------------------
// DIAGNOSTIC: same-XCD L2-local sync protocol, with runtime XCD claiming and
// payload verification. Verdict is TIME-ENCODED in dur_us:
//   works       -> ~25-60 us extra
//   unbalanced  -> ~+215 us  (XCD claim != 32 per die)
//   stale reads -> ~+535 us  (L2-local coherence model wrong)
// Scratch-only; never touches d_out.
// ---------------------------------------------------------------------------
__global__ __launch_bounds__(512) void diag_xcd(uint_t* __restrict__ ctl,
                                                uint_t* __restrict__ hD) {
  __shared__ uint_t sh[4];
  __shared__ int bad;
  const int tid = threadIdx.x;
  const int lane = tid & 63;
  const int wid = tid >> 6;

  uint_t xcd;
  asm("s_getreg_b32 %0, hwreg(HW_REG_XCC_ID)" : "=s"(xcd));

  if (tid == 0) {
    bad = 0;
    const uint_t slot = atomicAdd(&ctl[(xcd & 7) * 16], 1u);
    __hip_atomic_fetch_add(&ctl[128], 1u, __ATOMIC_RELAXED, __HIP_MEMORY_SCOPE_AGENT);
    sh[0] = xcd & 7;
    sh[1] = slot;
    uint_t it = 0;
    while (__hip_atomic_load(&ctl[128], __ATOMIC_RELAXED,
                             __HIP_MEMORY_SCOPE_AGENT) < 256u) {
      __builtin_amdgcn_s_sleep(1);
      if (++it > 200000u) break;
    }
    uint_t ok = 1;
    for (int i = 0; i < 8; ++i)
      ok &= (__hip_atomic_load(&ctl[i * 16], __ATOMIC_RELAXED,
                               __HIP_MEMORY_SCOPE_AGENT) == 32u);
    sh[2] = ok;
  }
  __syncthreads();
  const uint_t gp = sh[0];
  const uint_t slot = sh[1];
  const uint_t balanced = sh[2];

  if (!balanced || slot >= 32u) {
    for (int i = 0; i < 8000; ++i) __builtin_amdgcn_s_sleep(1);  // punish A
    return;
  }

  uint_t* arrD = ctl + 512;
  uint_t mism = 0;

  for (int t = 0; t < 64; ++t) {
    if (t > 0) {
      if (wid == 0) {
        const uint_t* aw = arrD + ((gp * 32 + (lane & 31)) * 8);
        uint_t it = 0;
        for (;;) {
          uint_t v;
          asm volatile(
              "global_load_dword %0, %1, off sc0\n\t"
              "s_waitcnt vmcnt(0)"
              : "=v"(v) : "v"(aw) : "memory");
          if (__all((int)v >= t)) break;
          __builtin_amdgcn_s_sleep(1);
          if (++it > 200000u) break;
        }
      }
      __syncthreads();
      // read peers' generation-t payloads: plain cached loads, fresh addrs,
      // served by the SAME XCD's L2 (writer and reader share the die).
      const int pr = tid >> 4;   // peer 0..31
      const int w = tid & 15;
      const uint_t v = hD[(((size_t)(t - 1) * 8 + gp) * 32 + pr) * 128 + w];
      mism += (v != (uint_t)t);
    }
    if (tid < 128)
      hD[(((size_t)t * 8 + gp) * 32 + slot) * 128 + tid] = (uint_t)(t + 1);
    asm volatile("s_waitcnt vmcnt(0)" ::: "memory");  // h drained to local L2
    __syncthreads();
    if (tid == 0)
      arrD[(gp * 32 + slot) * 8] = (uint_t)(t + 1);   // plain store -> local L2
  }

  if (mism) atomicAdd(&bad, (int)mism);
  __syncthreads();
  if (bad) {
    if (tid == 0)
      for (int i = 0; i < 20000; ++i) __builtin_amdgcn_s_sleep(1);  // punish B
    __syncthreads();
  }
}

extern "C" void kernel_launch(void* const* d_in, const int* in_sizes, int n_in,
                              void* d_out, int out_size, void* d_ws, size_t ws_size,
                              hipStream_t stream) {
  (void)in_sizes; (void)n_in; (void)out_size; (void)ws_size;
  const float* x = (const float*)d_in[0];
  const float* h0 = (const float*)d_in[1];
  const float* c0 = (const float*)d_in[2];
  const float* reset = (const float*)d_in[3];
  const float* W = (const float*)d_in[4];
  const float* bias = (const float*)d_in[5];
  float* out = (float*)d_out;

  const size_t TB = (size_t)T_STEPS * B_SZ;  // 16384
  const size_t SE = (size_t)B_SZ * H_SZ;     // 131072

  // ws layout (~227 MB; proven ws_size >= 269 MB in R1)
  char* p = (char*)d_ws;
  uint_t* bar = (uint_t*)p;               p += 16384;
  uint_t* dctl = (uint_t*)p;              p += 16384;
  ushort_t* WT = (ushort_t*)p;            p += (size_t)G4 * KW * 2;
  ushort_t* xbf = (ushort_t*)p;           p += TB * D_SZ * 2;
  ushort_t* xwg = (ushort_t*)p;           p += TB * G4 * 2;
  ushort_t* hbf0 = (ushort_t*)p;          p += SE * 2;
  ushort_t* hring = (ushort_t*)p;         p += (size_t)T_STEPS * SE * 2;
  uint_t* hD = (uint_t*)p;                p += (size_t)64 * 8 * 32 * 128 * 4;  // 8.4MB

  hipMemsetAsync(bar, 0, 32768, stream);  // covers bar + dctl
  convert_x<<<dim3((int)(TB * D_SZ / 8 / 256)), 256, 0, stream>>>(x, xbf);
  transpose_w<<<dim3(KW / 32, G4 / 32), 256, 0, stream>>>(W, WT);
  init_state<<<dim3((int)((SE + 255) / 256)), 256, 0, stream>>>(h0, reset, hbf0);
  xw_mfma3<<<dim3(4096), 256, 0, stream>>>(xbf, WT, bias, xwg);

  lstm_persist7<<<dim3(256), 512, 0, stream>>>(hbf0, c0, reset, xwg, WT, out, hring, bar);

  // diagnostic: verdict encoded in this dispatch's duration (see header)
  diag_xcd<<<dim3(256), 512, 0, stream>>>(dctl, hD);
}

// Round 16
// 779.087 us; speedup vs baseline: 2132.2988x; 2132.2988x over previous
//
#include <hip/hip_runtime.h>
#include <math.h>

#define T_STEPS 128
#define B_SZ 128
#define D_SZ 1024
#define H_SZ 1024
#define G4 4096
#define KW 2048  // rows of W = D+H

typedef __attribute__((ext_vector_type(8))) short bf16x8;
typedef __attribute__((ext_vector_type(4))) float f32x4;
typedef unsigned short ushort_t;
typedef unsigned int uint_t;
typedef unsigned long long ull_t;

__device__ __forceinline__ float sigf(float x) { return 1.0f / (1.0f + __expf(-x)); }
__device__ __forceinline__ float tanhfast(float x) { return 1.0f - 2.0f * sigf(-2.0f * x); }

__device__ __forceinline__ ushort_t f2bf(float f) {
  uint_t u = __float_as_uint(f);
  return (ushort_t)((u + 0x7fffu + ((u >> 16) & 1u)) >> 16);
}
__device__ __forceinline__ float bf2f(ushort_t s) {
  return __uint_as_float(((uint_t)s) << 16);
}

#define GLOAD_LDS16(gp, lp)                                                  \
  __builtin_amdgcn_global_load_lds(                                          \
      (const __attribute__((address_space(1))) unsigned int*)(const void*)(gp), \
      (__attribute__((address_space(3))) unsigned int*)(void*)(lp), 16, 0, 0)

// ---------------------------------------------------------------------------
// x fp32 [16384][1024] -> bf16 same layout. 8 elems/thread.
// ---------------------------------------------------------------------------
__global__ __launch_bounds__(256) void convert_x(const float* __restrict__ x,
                                                 ushort_t* __restrict__ xbf) {
  const size_t i8 = ((size_t)blockIdx.x * 256 + threadIdx.x) * 8;
  if (i8 + 8 > (size_t)T_STEPS * B_SZ * D_SZ) return;
  float4 a = *(const float4*)&x[i8];
  float4 b = *(const float4*)&x[i8 + 4];
  ushort_t o[8] = {f2bf(a.x), f2bf(a.y), f2bf(a.z), f2bf(a.w),
                   f2bf(b.x), f2bf(b.y), f2bf(b.z), f2bf(b.w)};
  *(uint4*)&xbf[i8] = *(uint4*)o;
}

// ---------------------------------------------------------------------------
// W fp32 [2048][4096] -> WT bf16 [4096][2048]  (WT[n][k] = W[k][n])
// ---------------------------------------------------------------------------
__global__ __launch_bounds__(256) void transpose_w(const float* __restrict__ W,
                                                   ushort_t* __restrict__ WT) {
  __shared__ float t[32][33];
  const int tx = threadIdx.x & 31;
  const int ty = threadIdx.x >> 5;  // 0..7
  const int k0 = blockIdx.x * 32;
  const int n0 = blockIdx.y * 32;
#pragma unroll
  for (int i = 0; i < 4; ++i)
    t[ty + i * 8][tx] = W[(size_t)(k0 + ty + i * 8) * G4 + n0 + tx];
  __syncthreads();
#pragma unroll
  for (int i = 0; i < 4; ++i)
    WT[(size_t)(n0 + ty + i * 8) * KW + k0 + tx] = f2bf(t[tx][ty + i * 8]);
}

// ---------------------------------------------------------------------------
// hbf0 = bf16(h0 * (1-reset[0]))
// ---------------------------------------------------------------------------
__global__ __launch_bounds__(256) void init_state(const float* __restrict__ h0,
                                                  const float* __restrict__ reset0,
                                                  ushort_t* __restrict__ hbf0) {
  const int i = blockIdx.x * 256 + threadIdx.x;
  if (i >= B_SZ * H_SZ) return;
  hbf0[i] = f2bf(h0[i] * (1.0f - reset0[i >> 10]));
}

// ---------------------------------------------------------------------------
// Gate pre-activation from x (v3 layout, supertile-swizzled).
//   elem idx = (((t*4 + btp)*64 + jt)*2048) + g*512 + c*32 + r32
//   m = t*128 + btp*32 + r32, n = g*1024 + jt*16 + c.
// ---------------------------------------------------------------------------
__global__ __launch_bounds__(256) void xw_mfma3(const ushort_t* __restrict__ xbf,
                                                const ushort_t* __restrict__ WT,
                                                const float* __restrict__ bias,
                                                ushort_t* __restrict__ xwg) {
  __shared__ ushort_t Asb[2][128 * 64];
  __shared__ ushort_t Bsb[2][128 * 64];

  const int bid = blockIdx.x;
  const int xcd = bid & 7;
  const int ib = bid >> 3;
  const int mt = (ib >> 5) * 8 + (ib & 7);
  const int nt = xcd * 4 + ((ib >> 3) & 3);
  const int m0 = mt * 128, n0 = nt * 128;
  const int tid = threadIdx.x, lane = tid & 63, wid = tid >> 6;
  const int wr = wid >> 1, wc = wid & 1;
  const int lr = lane & 15, ko = lane >> 4;
  const int srow = lane >> 3;
  const int skb = (lane & 7) * 16;

  f32x4 acc[4][4] = {};

#define XW_STAGE(buf, kt)                                                      \
  {                                                                            \
    const int k0b = (kt) * 128;                                                \
    _Pragma("unroll") for (int i = 0; i < 4; ++i) {                            \
      const int c = wid * 4 + i;                                               \
      const int row = c * 8 + srow;                                            \
      const int sw = skb ^ ((row & 7) << 4);                                   \
      GLOAD_LDS16((const char*)xbf + (size_t)(m0 + row) * 2048 + k0b + sw,     \
                  (char*)&Asb[buf][0] + c * 1024);                             \
      GLOAD_LDS16((const char*)WT + (size_t)(n0 + row) * 4096 + k0b + sw,      \
                  (char*)&Bsb[buf][0] + c * 1024);                             \
    }                                                                          \
  }

  XW_STAGE(0, 0);
  __syncthreads();
  const int xsw = (lr & 7) << 4;
  for (int kt = 0; kt < 16; ++kt) {
    if (kt + 1 < 16) XW_STAGE((kt + 1) & 1, kt + 1);
    const char* Ab = (const char*)&Asb[kt & 1][0] + (wr * 64 + lr) * 128;
    const char* Bb = (const char*)&Bsb[kt & 1][0] + (wc * 64 + lr) * 128;
#pragma unroll
    for (int ks = 0; ks < 2; ++ks) {
      const int kb = (ks * 64 + ko * 16) ^ xsw;
      bf16x8 a[4], b[4];
#pragma unroll
      for (int mi = 0; mi < 4; ++mi) a[mi] = *(const bf16x8*)(Ab + mi * 2048 + kb);
#pragma unroll
      for (int ni = 0; ni < 4; ++ni) b[ni] = *(const bf16x8*)(Bb + ni * 2048 + kb);
#pragma unroll
      for (int mi = 0; mi < 4; ++mi)
#pragma unroll
        for (int ni = 0; ni < 4; ++ni)
          acc[mi][ni] = __builtin_amdgcn_mfma_f32_16x16x32_bf16(a[mi], b[ni], acc[mi][ni], 0, 0, 0);
    }
    __syncthreads();
  }

  const int rr = ko * 4;
#pragma unroll
  for (int ni = 0; ni < 4; ++ni) {
    const int n = n0 + wc * 64 + ni * 16 + lr;
    const int g = n >> 10;
    const int jtn = (n & 1023) >> 4;
    const float bn = bias[n];
#pragma unroll
    for (int mi = 0; mi < 4; ++mi) {
      const int m = m0 + wr * 64 + mi * 16 + rr;
      const int tt = m >> 7;
      const int btp = (m & 127) >> 5;
      const int r32 = m & 31;
      ushort_t tmp[4];
#pragma unroll
      for (int r = 0; r < 4; ++r) tmp[r] = f2bf(acc[mi][ni][r] + bn);
      *(ull_t*)(xwg + (((size_t)tt * 4 + btp) * 64 + jtn) * 2048 + g * 512 + lr * 32 + r32) =
          *(ull_t*)tmp;
    }
  }
}

// ---------------------------------------------------------------------------
// Persistent LSTM recurrence v7 (known-good ~597us). 256 blocks (1/CU) x 512.
// Block (jt=bid&63, btp=bid>>6) touches only h rows [btp*32,+32): 4
// independent groups of 64 blocks; own-word arrival + direct 64-lane poll.
// h transport: per-step ring (sc write-through store, read once via cached
// global_load_lds -> same-XCD L2 dedup). Wh resident: LDS half + breg half.
// ---------------------------------------------------------------------------
__global__ __launch_bounds__(512) void lstm_persist7(
    const ushort_t* __restrict__ hbf0,
    const float* __restrict__ c0,
    const float* __restrict__ reset,
    const ushort_t* __restrict__ xwg,
    const ushort_t* __restrict__ WT,
    float* __restrict__ out,
    ushort_t* __restrict__ hring,
    uint_t* __restrict__ bar) {
  __shared__ ushort_t WhL[64 * 512];
  __shared__ ushort_t Ah[32 * 1024];
  __shared__ float sc[2][4][16][17];

  const int tid = threadIdx.x;
  const int bid = blockIdx.x;
  const int jt = bid & 63;
  const int btp = bid >> 6;
  const int b0 = btp * 32;
  const int lane = tid & 63;
  const int wid = tid >> 6;
  const int g = wid & 3;
  const int mh = wid >> 2;
  const int lr = lane & 15;
  const int ko = lane >> 4;
  const size_t SE = (size_t)B_SZ * H_SZ;

  uint_t* const arr = bar + btp * 256;

  for (int p = 0; p < 8; ++p) {
    const int id = p * 512 + tid;
    const int wrw = id >> 6;
    const int kb = (id & 63) * 16;
    const int n = (wrw >> 4) * H_SZ + jt * 16 + (wrw & 15);
    const uint4 v = *(const uint4*)((const char*)WT + (size_t)n * 4096 + 2048 + kb);
    *(uint4*)((char*)WhL + wrw * 1024 + (kb ^ ((wrw & 7) << 4))) = v;
  }

  const char* wrow = (const char*)WT + (size_t)(g * H_SZ + jt * 16 + lr) * 4096;
  bf16x8 breg[16];
#pragma unroll
  for (int q = 0; q < 16; ++q)
    breg[q] = *(const bf16x8*)(wrow + 3072 + q * 64 + ko * 16);

  const int row = tid >> 4;
  const int col = tid & 15;
  const int b = b0 + row;
  const int j = jt * 16 + col;
  const size_t so = (size_t)b * H_SZ + j;
  float creg = c0[so] * (1.0f - reset[b]);

  const int swzl = (lr & 7) << 4;
  const char* aBase = (const char*)Ah + (mh * 16 + lr) * 2048;
  const char* bBase = (const char*)WhL + (g * 16 + lr) * 1024;

  ushort_t xq0, xq1, xq2, xq3;
  {
    const ushort_t* xp = xwg + (((size_t)btp) * 64 + jt) * 2048 + col * 32 + row;
    xq0 = xp[0]; xq1 = xp[512]; xq2 = xp[1024]; xq3 = xp[1536];
  }
  float mn = 1.0f - reset[B_SZ + b];

  for (int t = 0; t < T_STEPS; ++t) {
    if (t > 0) {
      if (wid == 0) {
        uint_t it = 0;
        for (;;) {
          const uint_t v = __hip_atomic_load(&arr[lane], __ATOMIC_RELAXED,
                                             __HIP_MEMORY_SCOPE_AGENT);
          if (__all((int)v >= t)) break;
          __builtin_amdgcn_s_sleep(1);
          if (++it > 1000000u) break;
        }
      }
      __syncthreads();
    }
    const char* hsrc = (t == 0) ? (const char*)hbf0
                                : (const char*)(hring + (size_t)t * SE);
#pragma unroll
    for (int i = 0; i < 8; ++i) {
      const int c = wid * 8 + i;
      const int hrow = c >> 1;
      const int half = (c & 1) * 1024;
      const int kb = half + lane * 16;
      const int src = kb ^ ((hrow & 7) << 4);
      GLOAD_LDS16(hsrc + (size_t)(b0 + hrow) * 2048 + src,
                  (char*)Ah + hrow * 2048 + half);
    }
    __syncthreads();

    f32x4 ac0 = {}, ac1 = {}, ac2 = {}, ac3 = {};
#pragma unroll
    for (int q = 0; q < 4; ++q) {
      bf16x8 a0 = *(const bf16x8*)(aBase + (((q * 4 + 0) * 64 + ko * 16) ^ swzl));
      bf16x8 b0f = *(const bf16x8*)(bBase + (((q * 4 + 0) * 64 + ko * 16) ^ swzl));
      ac0 = __builtin_amdgcn_mfma_f32_16x16x32_bf16(a0, b0f, ac0, 0, 0, 0);
      bf16x8 a1 = *(const bf16x8*)(aBase + (((q * 4 + 1) * 64 + ko * 16) ^ swzl));
      bf16x8 b1f = *(const bf16x8*)(bBase + (((q * 4 + 1) * 64 + ko * 16) ^ swzl));
      ac1 = __builtin_amdgcn_mfma_f32_16x16x32_bf16(a1, b1f, ac1, 0, 0, 0);
      bf16x8 a2 = *(const bf16x8*)(aBase + (((q * 4 + 2) * 64 + ko * 16) ^ swzl));
      bf16x8 b2f = *(const bf16x8*)(bBase + (((q * 4 + 2) * 64 + ko * 16) ^ swzl));
      ac2 = __builtin_amdgcn_mfma_f32_16x16x32_bf16(a2, b2f, ac2, 0, 0, 0);
      bf16x8 a3 = *(const bf16x8*)(aBase + (((q * 4 + 3) * 64 + ko * 16) ^ swzl));
      bf16x8 b3f = *(const bf16x8*)(bBase + (((q * 4 + 3) * 64 + ko * 16) ^ swzl));
      ac3 = __builtin_amdgcn_mfma_f32_16x16x32_bf16(a3, b3f, ac3, 0, 0, 0);
    }
#pragma unroll
    for (int q = 0; q < 4; ++q) {
      bf16x8 a0 = *(const bf16x8*)(aBase + (((16 + q * 4 + 0) * 64 + ko * 16) ^ swzl));
      ac0 = __builtin_amdgcn_mfma_f32_16x16x32_bf16(a0, breg[q * 4 + 0], ac0, 0, 0, 0);
      bf16x8 a1 = *(const bf16x8*)(aBase + (((16 + q * 4 + 1) * 64 + ko * 16) ^ swzl));
      ac1 = __builtin_amdgcn_mfma_f32_16x16x32_bf16(a1, breg[q * 4 + 1], ac1, 0, 0, 0);
      bf16x8 a2 = *(const bf16x8*)(aBase + (((16 + q * 4 + 2) * 64 + ko * 16) ^ swzl));
      ac2 = __builtin_amdgcn_mfma_f32_16x16x32_bf16(a2, breg[q * 4 + 2], ac2, 0, 0, 0);
      bf16x8 a3 = *(const bf16x8*)(aBase + (((16 + q * 4 + 3) * 64 + ko * 16) ^ swzl));
      ac3 = __builtin_amdgcn_mfma_f32_16x16x32_bf16(a3, breg[q * 4 + 3], ac3, 0, 0, 0);
    }
    const f32x4 acc = (ac0 + ac1) + (ac2 + ac3);
#pragma unroll
    for (int r = 0; r < 4; ++r) sc[mh][g][ko * 4 + r][lr] = acc[r];
    __syncthreads();

    const float gi = sc[row >> 4][0][row & 15][col] + bf2f(xq0);
    const float gg = sc[row >> 4][1][row & 15][col] + bf2f(xq1);
    const float gf = sc[row >> 4][2][row & 15][col] + bf2f(xq2);
    const float go = sc[row >> 4][3][row & 15][col] + bf2f(xq3);
    const float f = sigf(gf + 1.0f);
    const float cn = f * creg + sigf(gi) * tanhfast(gg);
    const float hn = sigf(go) * tanhfast(cn);
    creg = cn * mn;

    if (t < T_STEPS - 1) {
      const uint_t hm = (uint_t)f2bf(hn * mn);
      const uint_t h1 = (uint_t)__shfl_down((int)hm, 1);
      const uint_t h2 = (uint_t)__shfl_down((int)hm, 2);
      const uint_t h3 = (uint_t)__shfl_down((int)hm, 3);
      if ((col & 3) == 0) {
        const ull_t pk = (ull_t)(hm & 0xffffu) | ((ull_t)(h1 & 0xffffu) << 16) |
                         ((ull_t)(h2 & 0xffffu) << 32) | ((ull_t)(h3 & 0xffffu) << 48);
        __hip_atomic_store((ull_t*)(hring + (size_t)(t + 1) * SE + so), pk,
                           __ATOMIC_RELAXED, __HIP_MEMORY_SCOPE_AGENT);
      }
      asm volatile("s_waitcnt vmcnt(0)" ::: "memory");
      __syncthreads();
      if (tid == 0)
        __hip_atomic_store(&arr[jt], (uint_t)(t + 1),
                           __ATOMIC_RELAXED, __HIP_MEMORY_SCOPE_AGENT);
      out[(size_t)t * SE + so] = hn;
      const ushort_t* xp = xwg + (((size_t)(t + 1) * 4 + btp) * 64 + jt) * 2048 + col * 32 + row;
      xq0 = xp[0]; xq1 = xp[512]; xq2 = xp[1024]; xq3 = xp[1536];
      mn = (t + 1 < T_STEPS - 1) ? (1.0f - reset[(size_t)(t + 2) * B_SZ + b]) : 1.0f;
    } else {
      out[(size_t)t * SE + so] = hn;
      float* hT = out + (size_t)T_STEPS * SE;
      float* cT = hT + SE;
      hT[so] = hn;
      cT[so] = cn;
    }
  }
}

extern "C" void kernel_launch(void* const* d_in, const int* in_sizes, int n_in,
                              void* d_out, int out_size, void* d_ws, size_t ws_size,
                              hipStream_t stream) {
  (void)in_sizes; (void)n_in; (void)out_size; (void)ws_size;
  const float* x = (const float*)d_in[0];
  const float* h0 = (const float*)d_in[1];
  const float* c0 = (const float*)d_in[2];
  const float* reset = (const float*)d_in[3];
  const float* W = (const float*)d_in[4];
  const float* bias = (const float*)d_in[5];
  float* out = (float*)d_out;

  const size_t TB = (size_t)T_STEPS * B_SZ;  // 16384
  const size_t SE = (size_t)B_SZ * H_SZ;     // 131072

  // ws layout (~218 MB; proven ws_size >= 269 MB in R1)
  char* p = (char*)d_ws;
  uint_t* bar = (uint_t*)p;               p += 16384;
  ushort_t* WT = (ushort_t*)p;            p += (size_t)G4 * KW * 2;
  ushort_t* xbf = (ushort_t*)p;           p += TB * D_SZ * 2;
  ushort_t* xwg = (ushort_t*)p;           p += TB * G4 * 2;
  ushort_t* hbf0 = (ushort_t*)p;          p += SE * 2;
  ushort_t* hring = (ushort_t*)p;         p += (size_t)T_STEPS * SE * 2;

  hipMemsetAsync(bar, 0, 16384, stream);
  convert_x<<<dim3((int)(TB * D_SZ / 8 / 256)), 256, 0, stream>>>(x, xbf);
  transpose_w<<<dim3(KW / 32, G4 / 32), 256, 0, stream>>>(W, WT);
  init_state<<<dim3((int)((SE + 255) / 256)), 256, 0, stream>>>(h0, reset, hbf0);
  xw_mfma3<<<dim3(4096), 256, 0, stream>>>(xbf, WT, bias, xwg);

  lstm_persist7<<<dim3(256), 512, 0, stream>>>(hbf0, c0, reset, xwg, WT, out, hring, bar);
}